// Round 13
// baseline (1632.545 us; speedup 1.0000x reference)
//
#include <hip/hip_runtime.h>
#include <hip/hip_bf16.h>

// Problem constants
#define BB 16
#define NN 8192
#define SS 1024
#define GG 32
// sortable(1.0f) = 0x3F800000 ^ 0x80000000
#define SORT_R2 0xBF800000u

typedef float v2f __attribute__((ext_vector_type(2)));

__device__ __forceinline__ unsigned sortable(float f) {
    unsigned u = __float_as_uint(f);
    return u ^ ((unsigned)(((int)u) >> 31) | 0x80000000u);
}

// f32 max-combine with a DPP-permuted copy (2 slots: v_mov_dpp + v_max_f32).
// row_shr:n = 0x110|n, row_bcast15 = 0x142, row_bcast31 = 0x143.
template <int CTRL, int RM>
__device__ __forceinline__ float dpp_maxf(float v) {
    int i = __float_as_int(v);
    int p = __builtin_amdgcn_update_dpp(i, i, CTRL, RM, 0xF, false);
    return fmaxf(v, __int_as_float(p));
}

template <int CTRL, int RM>
__device__ __forceinline__ float dpp_minf(float v) {
    int i = __float_as_int(v);
    int p = __builtin_amdgcn_update_dpp(i, i, CTRL, RM, 0xF, false);
    return fminf(v, __int_as_float(p));
}

// u32 min-combine with a DPP-permuted copy (2 slots).
template <int CTRL, int RM>
__device__ __forceinline__ unsigned dpp_minu(unsigned v) {
    int p = __builtin_amdgcn_update_dpp((int)v, (int)v, CTRL, RM, 0xF, false);
    return min(v, (unsigned)p);
}

__device__ __forceinline__ float fmax3(float a, float b, float c) {
    return fmaxf(fmaxf(a, b), c);   // fuses to v_max3_f32
}

// spread low 6 bits to every 3rd bit position (Morton interleave)
__device__ __forceinline__ unsigned spread3(unsigned c) {
    unsigned r = 0;
#pragma unroll
    for (int b = 0; b < 6; b++) r |= ((c >> b) & 1u) << (3 * b);
    return r;
}

// ---------------------------------------------------------------------------
// Kernel 1: pack pts4[b][n] = {x, y, z, (x*x+y*y)+z*z}  (rn ops, no contraction)
// ---------------------------------------------------------------------------
__global__ __launch_bounds__(256) void k_pts(const float* __restrict__ coor,
                                             float4* __restrict__ pts4) {
    int i = blockIdx.x * 256 + threadIdx.x;   // 0 .. B*N-1
    int b = i >> 13, n = i & (NN - 1);
    const float* cb = coor + (long)b * 3 * NN;
    float x = cb[n], y = cb[NN + n], z = cb[2 * NN + n];
    float pn = __fadd_rn(__fadd_rn(__fmul_rn(x, x), __fmul_rn(y, y)), __fmul_rn(z, z));
    pts4[i] = make_float4(x, y, z, pn);
}

// ---------------------------------------------------------------------------
// Kernel 2: transpose fea (B,64,N) -> feaT (B,N,64)
// ---------------------------------------------------------------------------
__global__ __launch_bounds__(256) void k_tr(const float* __restrict__ fea,
                                            float* __restrict__ feaT) {
    __shared__ float tile[64][65];
    int b = blockIdx.y, n0 = blockIdx.x * 64;
    int t = threadIdx.x;
    int nl = t & 63, cb = t >> 6;
#pragma unroll
    for (int i = 0; i < 16; i++) {
        int c = cb * 16 + i;
        tile[nl][c] = fea[((long)b * 64 + c) * NN + n0 + nl];
    }
    __syncthreads();
    int cl = t & 63, nb = t >> 6;
#pragma unroll
    for (int i = 0; i < 16; i++) {
        int n = nb * 16 + i;
        feaT[((long)b * NN + n0 + n) * 64 + cl] = tile[n][cl];
    }
}

// ---------------------------------------------------------------------------
// Kernel 3: farthest point sampling. One block (512 thr) per batch.
// v10: v5's two-barrier value-first scheme + PROVABLY-SAFE GROUP SKIPPING.
// Init: Morton-sort point indices (u32 (morton18<<13)|idx keys, bitonic in
// LDS — swap-only, so any sort bug degrades perf, never correctness); each
// thread owns 16 Morton-contiguous points with a register bbox. Per step:
// lb = dist(centroid, bbox)^2; skip the group update iff
// lb*(1-2^-16) >= bv (per-thread max dist). Safety: lb_true <= d_true,
// d_new_computed >= d_true(1-6*2^-24), lb_computed <= lb_true(1+6*2^-24)
// => skip implies min(dist, d_new) == dist elementwise: bit-exact no-op.
// Value reduction (f32 DPP max) is order-independent; winner path takes
// min over ORIGINAL indices via atomicMin => exact jnp.argmax ties.
// ---------------------------------------------------------------------------
__global__ __launch_bounds__(512, 2) void k_fps(const float4* __restrict__ pts4,
                                                float4* __restrict__ qpts,
                                                float* __restrict__ out) {
#pragma clang fp contract(off)
    __shared__ float xs[NN], ys[NN], zs[NN];
    __shared__ int scur[SS];
    __shared__ unsigned skey[NN];
    __shared__ __align__(16) float redv[2][8];
    __shared__ float bbred[6][8];
    __shared__ int sidx[2];
    int b = blockIdx.x;
    int t = threadIdx.x;
    const float4* P = pts4 + (long)b * NN;

    // ---- init: load points, local bbox ----
    float lminx = 1e30f, lmaxx = -1e30f;
    float lminy = 1e30f, lmaxy = -1e30f;
    float lminz = 1e30f, lmaxz = -1e30f;
#pragma unroll
    for (int j = 0; j < 16; j++) {
        int p = t + j * 512;
        float4 v = P[p];
        xs[p] = v.x; ys[p] = v.y; zs[p] = v.z;
        lminx = fminf(lminx, v.x); lmaxx = fmaxf(lmaxx, v.x);
        lminy = fminf(lminy, v.y); lmaxy = fmaxf(lmaxy, v.y);
        lminz = fminf(lminz, v.z); lmaxz = fmaxf(lmaxz, v.z);
    }
    if (t == 0) { sidx[0] = 0x7FFFFFFF; sidx[1] = 0x7FFFFFFF; }
    // wave-reduce bbox, lane 63 publishes
    lminx = dpp_minf<0x111,0xF>(lminx); lminx = dpp_minf<0x112,0xF>(lminx);
    lminx = dpp_minf<0x114,0xF>(lminx); lminx = dpp_minf<0x118,0xF>(lminx);
    lminx = dpp_minf<0x142,0xA>(lminx); lminx = dpp_minf<0x143,0xC>(lminx);
    lminy = dpp_minf<0x111,0xF>(lminy); lminy = dpp_minf<0x112,0xF>(lminy);
    lminy = dpp_minf<0x114,0xF>(lminy); lminy = dpp_minf<0x118,0xF>(lminy);
    lminy = dpp_minf<0x142,0xA>(lminy); lminy = dpp_minf<0x143,0xC>(lminy);
    lminz = dpp_minf<0x111,0xF>(lminz); lminz = dpp_minf<0x112,0xF>(lminz);
    lminz = dpp_minf<0x114,0xF>(lminz); lminz = dpp_minf<0x118,0xF>(lminz);
    lminz = dpp_minf<0x142,0xA>(lminz); lminz = dpp_minf<0x143,0xC>(lminz);
    lmaxx = dpp_maxf<0x111,0xF>(lmaxx); lmaxx = dpp_maxf<0x112,0xF>(lmaxx);
    lmaxx = dpp_maxf<0x114,0xF>(lmaxx); lmaxx = dpp_maxf<0x118,0xF>(lmaxx);
    lmaxx = dpp_maxf<0x142,0xA>(lmaxx); lmaxx = dpp_maxf<0x143,0xC>(lmaxx);
    lmaxy = dpp_maxf<0x111,0xF>(lmaxy); lmaxy = dpp_maxf<0x112,0xF>(lmaxy);
    lmaxy = dpp_maxf<0x114,0xF>(lmaxy); lmaxy = dpp_maxf<0x118,0xF>(lmaxy);
    lmaxy = dpp_maxf<0x142,0xA>(lmaxy); lmaxy = dpp_maxf<0x143,0xC>(lmaxy);
    lmaxz = dpp_maxf<0x111,0xF>(lmaxz); lmaxz = dpp_maxf<0x112,0xF>(lmaxz);
    lmaxz = dpp_maxf<0x114,0xF>(lmaxz); lmaxz = dpp_maxf<0x118,0xF>(lmaxz);
    lmaxz = dpp_maxf<0x142,0xA>(lmaxz); lmaxz = dpp_maxf<0x143,0xC>(lmaxz);
    if ((t & 63) == 63) {
        int w = t >> 6;
        bbred[0][w] = lminx; bbred[1][w] = lmaxx;
        bbred[2][w] = lminy; bbred[3][w] = lmaxy;
        bbred[4][w] = lminz; bbred[5][w] = lmaxz;
    }
    __syncthreads();
    float bminx = bbred[0][0], bmaxx = bbred[1][0];
    float bminy = bbred[2][0], bmaxy = bbred[3][0];
    float bminz = bbred[4][0], bmaxz = bbred[5][0];
#pragma unroll
    for (int w = 1; w < 8; w++) {
        bminx = fminf(bminx, bbred[0][w]); bmaxx = fmaxf(bmaxx, bbred[1][w]);
        bminy = fminf(bminy, bbred[2][w]); bmaxy = fmaxf(bmaxy, bbred[3][w]);
        bminz = fminf(bminz, bbred[4][w]); bmaxz = fmaxf(bmaxz, bbred[5][w]);
    }
    float sxs = 63.0f / fmaxf(bmaxx - bminx, 1e-20f);
    float sys = 63.0f / fmaxf(bmaxy - bminy, 1e-20f);
    float szs = 63.0f / fmaxf(bmaxz - bminz, 1e-20f);
    // Morton keys
#pragma unroll
    for (int j = 0; j < 16; j++) {
        int p = t + j * 512;
        unsigned c0 = (unsigned)(int)fminf(63.f, fmaxf(0.f, (xs[p] - bminx) * sxs));
        unsigned c1 = (unsigned)(int)fminf(63.f, fmaxf(0.f, (ys[p] - bminy) * sys));
        unsigned c2 = (unsigned)(int)fminf(63.f, fmaxf(0.f, (zs[p] - bminz) * szs));
        unsigned mo = spread3(c0) | (spread3(c1) << 1) | (spread3(c2) << 2);
        skey[p] = (mo << 13) | (unsigned)p;
    }
    __syncthreads();
    // bitonic sort (ascending); swap-only => always a permutation
    for (int kk = 2; kk <= NN; kk <<= 1) {
        for (int jj = kk >> 1; jj > 0; jj >>= 1) {
#pragma unroll 1
            for (int m = 0; m < 16; m++) {
                int i = m * 512 + t;
                int ixj = i ^ jj;
                if (ixj > i) {
                    unsigned a = skey[i], c = skey[ixj];
                    bool up = ((i & kk) == 0);
                    if ((a > c) == up) { skey[i] = c; skey[ixj] = a; }
                }
            }
            __syncthreads();
        }
    }
    // gather my 16 Morton-contiguous points + group bbox + orig indices
    v2f px[8], py[8], pz[8], dist[8];
    int oidx[16];
    float gxmin = 1e30f, gxmax = -1e30f;
    float gymin = 1e30f, gymax = -1e30f;
    float gzmin = 1e30f, gzmax = -1e30f;
#pragma unroll
    for (int j = 0; j < 16; j++) {
        int o = (int)(skey[t * 16 + j] & (NN - 1));
        oidx[j] = o;
        float x = xs[o], y = ys[o], z = zs[o];
        gxmin = fminf(gxmin, x); gxmax = fmaxf(gxmax, x);
        gymin = fminf(gymin, y); gymax = fmaxf(gymax, y);
        gzmin = fminf(gzmin, z); gzmax = fmaxf(gzmax, z);
        int pr = j >> 1;
        if (j & 1) { px[pr].y = x; py[pr].y = y; pz[pr].y = z; }
        else       { px[pr].x = x; py[pr].x = y; pz[pr].x = z; }
    }
#pragma unroll
    for (int j = 0; j < 8; j++) dist[j] = v2f{1e10f, 1e10f};
    float bv = 1e10f;
    __syncthreads();

    int cur = 0;
    for (int s = 0; s < SS; s++) {
        int par = s & 1;
        float cx = xs[cur], cy = ys[cur], cz = zs[cur];
        if (t == 0) scur[s] = cur;
        // conservative lower bound of squared distance to group's bbox
        float ax = fmax3(gxmin - cx, cx - gxmax, 0.0f);
        float ay = fmax3(gymin - cy, cy - gymax, 0.0f);
        float az = fmax3(gzmin - cz, cz - gzmax, 0.0f);
        float lb = (ax * ax + ay * ay) + az * az;
        if (lb * 0.9999847412109375f < bv) {   // (1-2^-16) safety margin
            v2f cx2 = v2f{cx, cx}, cy2 = v2f{cy, cy}, cz2 = v2f{cz, cz};
#pragma unroll
            for (int j = 0; j < 8; j++) {
                v2f dx = px[j] - cx2;
                v2f dy = py[j] - cy2;
                v2f dz = pz[j] - cz2;
                v2f xx = dx * dx;
                v2f yy = dy * dy;
                v2f zz = dz * dz;
                v2f sm = xx + yy;
                v2f d = sm + zz;
                dist[j] = __builtin_elementwise_min(dist[j], d);
            }
            v2f m01 = __builtin_elementwise_max(dist[0], dist[1]);
            v2f m23 = __builtin_elementwise_max(dist[2], dist[3]);
            v2f m45 = __builtin_elementwise_max(dist[4], dist[5]);
            v2f m67 = __builtin_elementwise_max(dist[6], dist[7]);
            v2f m03 = __builtin_elementwise_max(m01, m23);
            v2f m47 = __builtin_elementwise_max(m45, m67);
            v2f m07 = __builtin_elementwise_max(m03, m47);
            bv = fmaxf(m07.x, m07.y);
        }
        // 64-lane DPP f32 max; full-wave max lands in lane 63
        float wv = bv;
        wv = dpp_maxf<0x111, 0xF>(wv);   // row_shr:1
        wv = dpp_maxf<0x112, 0xF>(wv);   // row_shr:2
        wv = dpp_maxf<0x114, 0xF>(wv);   // row_shr:4
        wv = dpp_maxf<0x118, 0xF>(wv);   // row_shr:8
        wv = dpp_maxf<0x142, 0xA>(wv);   // row_bcast:15 (rows 1,3)
        wv = dpp_maxf<0x143, 0xC>(wv);   // row_bcast:31 (rows 2,3)
        if ((t & 63) == 63) redv[par][t >> 6] = wv;
        __syncthreads();                 // barrier 1
        float4 r0 = *(const float4*)redv[par];
        float4 r1 = *(const float4*)(redv[par] + 4);
        float gmax = fmaxf(fmax3(r0.x, r0.y, r0.z),
                           fmax3(r0.w, fmax3(r1.x, r1.y, r1.z), r1.w));
        // reset the OTHER sidx slot (used at s+1); barrier 2 separates it
        // from s+1's atomics.
        if (t == 0) sidx[1 - par] = 0x7FFFFFFF;
        if (bv == gmax) {
            // block-rare path: lowest ORIGINAL index among max-holders
            int mi = 0x7FFFFFFF;
#pragma unroll
            for (int j = 0; j < 8; j++) {
                mi = min(mi, (dist[j].x == gmax) ? oidx[2 * j]     : 0x7FFFFFFF);
                mi = min(mi, (dist[j].y == gmax) ? oidx[2 * j + 1] : 0x7FFFFFFF);
            }
            atomicMin(&sidx[par], mi);
        }
        __syncthreads();                 // barrier 2
        cur = sidx[par];
    }
    __syncthreads();

    // epilogue: write new_coor (B,3,S) and query points from recorded indices
#pragma unroll
    for (int s = t; s < SS; s += 512) {
        int c = scur[s];
        float cx = xs[c], cy = ys[c], cz = zs[c];
        out[(long)b * 3 * SS + s]          = cx;
        out[(long)b * 3 * SS + SS + s]     = cy;
        out[(long)b * 3 * SS + 2 * SS + s] = cz;
        float qn = __fadd_rn(__fadd_rn(__fmul_rn(cx, cx), __fmul_rn(cy, cy)),
                             __fmul_rn(cz, cz));
        qpts[(long)b * SS + s] = make_float4(cx, cy, cz, qn);
    }
}

// ---------------------------------------------------------------------------
// Kernel 4 (FUSED knn+mlp): R12 verbatim (passed, absmax 0.0).
// ---------------------------------------------------------------------------
#define SKEW(p) ((p) + ((p) >> 5))
__global__ __launch_bounds__(64, 1) void k_knn_mlp(const float4* __restrict__ pts4,
                                                   const float* __restrict__ feaT,
                                                   const float4* __restrict__ qpts,
                                                   const float* __restrict__ W,
                                                   float* __restrict__ out) {
    __shared__ __align__(16) unsigned dk[NN + NN / 32];   // 33792 B
    __shared__ int sidxs[GG];
    float* grouped = (float*)dk;   // reused after pops: 32*68 floats (8704 B)

    int Q = blockIdx.x;                      // b*1024 + s
    int b = Q >> 10, s = Q & 1023;
    int l = threadIdx.x;
    float4 q = qpts[Q];
    const float4* P = pts4 + (long)b * NN;

    // ---- Phase 1: distance scan ----
    unsigned bmin = 0xFFFFFFFFu;
    int bpos = 0;
#pragma unroll 16
    for (int j = 0; j < 128; j++) {
        int p = j * 64 + l;
        float4 v = P[p];
        float dot = __fadd_rn(__fadd_rn(__fmul_rn(q.x, v.x), __fmul_rn(q.y, v.y)),
                              __fmul_rn(q.z, v.z));
        float d = __fadd_rn(__fsub_rn(q.w, __fmul_rn(2.0f, dot)), v.w);
        unsigned u = sortable(d);
        dk[SKEW(p)] = u;
        if (u < bmin) { bmin = u; bpos = p; }   // ascending p -> earliest index on tie
    }
    __syncthreads();

    // ---- Phase 2: W rows into registers (latency overlaps the pop loop) ----
    float wa[68], wb[68];
    {
        const float* Wr = W + l * 67;
#pragma unroll
        for (int c = 0; c < 67; c++) {
            wa[c] = Wr[c];
            wb[c] = Wr[64 * 67 + c];
        }
        wa[67] = 0.f; wb[67] = 0.f;
    }

    // ---- Phase 3: 32 pops ----
    unsigned resv = 0;
    int resp = 0, pos0 = 0;
    for (int k = 0; k < GG; k++) {
        unsigned mv = bmin;
        mv = dpp_minu<0x111, 0xF>(mv);
        mv = dpp_minu<0x112, 0xF>(mv);
        mv = dpp_minu<0x114, 0xF>(mv);
        mv = dpp_minu<0x118, 0xF>(mv);
        mv = dpp_minu<0x142, 0xA>(mv);
        mv = dpp_minu<0x143, 0xC>(mv);
        unsigned wmin = (unsigned)__builtin_amdgcn_readlane((int)mv, 63);
        unsigned long long mask = __ballot(bmin == wmin);
        int wpos;
        if (__builtin_popcountll(mask) == 1) {
            int owner = __builtin_ctzll(mask);
            wpos = __builtin_amdgcn_readlane(bpos, owner);
        } else {
            unsigned long long kk =
                ((unsigned long long)bmin << 32) | (unsigned)bpos;
#pragma unroll
            for (int m = 1; m < 64; m <<= 1) {
                unsigned long long o = __shfl_xor(kk, m, 64);
                kk = (o < kk) ? o : kk;
            }
            wpos = (int)(kk & 0xFFFFFFFFull);
        }
        if (k == 0) pos0 = wpos;
        if (l == k) { resv = wmin; resp = wpos; }
        int own = wpos & 63;
        if (l == own) dk[SKEW(wpos)] = 0xFFFFFFFFu;   // invalidate popped slot
        __syncthreads();
        // cooperative rescan of owner's column (its 128 points)
        int p1 = l * 64 + own;
        int p2 = (l + 64) * 64 + own;
        unsigned v1 = dk[SKEW(p1)], v2 = dk[SKEW(p2)];
        bool c = v2 < v1;                 // p1 < p2, so tie keeps earliest
        unsigned cv = c ? v2 : v1;
        int cp = c ? p2 : p1;
        unsigned cm = cv;
        cm = dpp_minu<0x111, 0xF>(cm);
        cm = dpp_minu<0x112, 0xF>(cm);
        cm = dpp_minu<0x114, 0xF>(cm);
        cm = dpp_minu<0x118, 0xF>(cm);
        cm = dpp_minu<0x142, 0xA>(cm);
        cm = dpp_minu<0x143, 0xC>(cm);
        unsigned colmin = (unsigned)__builtin_amdgcn_readlane((int)cm, 63);
        unsigned long long m2 = __ballot(cv == colmin);
        int colpos;
        if (__builtin_popcountll(m2) == 1) {
            colpos = __builtin_amdgcn_readlane(cp, __builtin_ctzll(m2));
        } else {
            unsigned long long kk =
                ((unsigned long long)cv << 32) | (unsigned)cp;
#pragma unroll
            for (int m = 1; m < 64; m <<= 1) {
                unsigned long long o = __shfl_xor(kk, m, 64);
                kk = (o < kk) ? o : kk;
            }
            colpos = (int)(kk & 0xFFFFFFFFull);
        }
        if (l == own) { bmin = colmin; bpos = colpos; }
        __syncthreads();
    }

    // ---- Phase 4: final indices + gather into reused LDS ----
    if (l < GG) sidxs[l] = (resv > SORT_R2) ? pos0 : resp;   // radius filter
    __syncthreads();   // sidxs visible; dk dead from here on

    if (l < 32) {
        int idx = sidxs[l];
        float4 p = pts4[(long)b * NN + idx];
        float4 rc = make_float4(__fsub_rn(p.x, q.x), __fsub_rn(p.y, q.y),
                                __fsub_rn(p.z, q.z), 0.f);
        *(float4*)&grouped[l * 68 + 64] = rc;
    }
    {
        int g = l >> 1, half = l & 1;
        int idx = sidxs[g];
        const float4* f4 = (const float4*)(feaT + ((long)b * NN + idx) * 64);
#pragma unroll
        for (int k4 = 0; k4 < 8; k4++) {
            *(float4*)&grouped[g * 68 + half * 32 + k4 * 4] = f4[half * 8 + k4];
        }
    }
    __syncthreads();

    // ---- Phase 5: 1x1 conv + relu + max over group ----
    float m0 = -1e30f, m1 = -1e30f;
#pragma unroll 2
    for (int g = 0; g < GG; g++) {
        float a0 = 0.f, a1 = 0.f;
#pragma unroll
        for (int c4 = 0; c4 < 17; c4++) {
            float4 gv = *(float4*)&grouped[g * 68 + c4 * 4];
            a0 = fmaf(gv.x, wa[4 * c4 + 0], a0);
            a0 = fmaf(gv.y, wa[4 * c4 + 1], a0);
            a0 = fmaf(gv.z, wa[4 * c4 + 2], a0);
            a0 = fmaf(gv.w, wa[4 * c4 + 3], a0);
            a1 = fmaf(gv.x, wb[4 * c4 + 0], a1);
            a1 = fmaf(gv.y, wb[4 * c4 + 1], a1);
            a1 = fmaf(gv.z, wb[4 * c4 + 2], a1);
            a1 = fmaf(gv.w, wb[4 * c4 + 3], a1);
        }
        m0 = fmaxf(m0, a0);
        m1 = fmaxf(m1, a1);
    }
    // outputs: (B,3,S) then (B,128,S); relu(max) == max(relu)
    out[49152 + ((long)b * 128 + l) * SS + s]      = fmaxf(m0, 0.f);
    out[49152 + ((long)b * 128 + l + 64) * SS + s] = fmaxf(m1, 0.f);
}

// ---------------------------------------------------------------------------
extern "C" void kernel_launch(void* const* d_in, const int* in_sizes, int n_in,
                              void* d_out, int out_size, void* d_ws, size_t ws_size,
                              hipStream_t stream) {
    const float* coor = (const float*)d_in[0];   // (16,3,8192)
    const float* fea  = (const float*)d_in[1];   // (16,64,8192)
    const float* Wm   = (const float*)d_in[2];   // (128,67)
    float* out = (float*)d_out;

    char* ws = (char*)d_ws;
    float4* pts4 = (float4*)ws;                               //  2 MB
    float*  feaT = (float*)(ws + 2097152);                    // 32 MB
    float4* qpts = (float4*)(ws + 2097152 + 33554432);        // 256 KB

    k_pts<<<(BB * NN) / 256, 256, 0, stream>>>(coor, pts4);
    k_tr<<<dim3(NN / 64, BB), 256, 0, stream>>>(fea, feaT);
    k_fps<<<BB, 512, 0, stream>>>(pts4, qpts, out);
    k_knn_mlp<<<BB * SS, 64, 0, stream>>>(pts4, feaT, qpts, Wm, out);
}

// Round 14
// 1439.730 us; speedup vs baseline: 1.1339x; 1.1339x over previous
//
#include <hip/hip_runtime.h>
#include <hip/hip_bf16.h>

// Problem constants
#define BB 16
#define NN 8192
#define SS 1024
#define GG 32
// sortable(1.0f) = 0x3F800000 ^ 0x80000000
#define SORT_R2 0xBF800000u

typedef float v2f __attribute__((ext_vector_type(2)));

__device__ __forceinline__ unsigned sortable(float f) {
    unsigned u = __float_as_uint(f);
    return u ^ ((unsigned)(((int)u) >> 31) | 0x80000000u);
}

// f32 max-combine with a DPP-permuted copy (2 slots: v_mov_dpp + v_max_f32).
// row_shr:n = 0x110|n, row_bcast15 = 0x142, row_bcast31 = 0x143.
template <int CTRL, int RM>
__device__ __forceinline__ float dpp_maxf(float v) {
    int i = __float_as_int(v);
    int p = __builtin_amdgcn_update_dpp(i, i, CTRL, RM, 0xF, false);
    return fmaxf(v, __int_as_float(p));
}

// u32 min-combine with a DPP-permuted copy (2 slots).
template <int CTRL, int RM>
__device__ __forceinline__ unsigned dpp_minu(unsigned v) {
    int p = __builtin_amdgcn_update_dpp((int)v, (int)v, CTRL, RM, 0xF, false);
    return min(v, (unsigned)p);
}

__device__ __forceinline__ float fmax3(float a, float b, float c) {
    return fmaxf(fmaxf(a, b), c);   // fuses to v_max3_f32
}

// ---------------------------------------------------------------------------
// Kernel 1: pack pts4[b][n] = {x, y, z, (x*x+y*y)+z*z}  (rn ops, no contraction)
// ---------------------------------------------------------------------------
__global__ __launch_bounds__(256) void k_pts(const float* __restrict__ coor,
                                             float4* __restrict__ pts4) {
    int i = blockIdx.x * 256 + threadIdx.x;   // 0 .. B*N-1
    int b = i >> 13, n = i & (NN - 1);
    const float* cb = coor + (long)b * 3 * NN;
    float x = cb[n], y = cb[NN + n], z = cb[2 * NN + n];
    float pn = __fadd_rn(__fadd_rn(__fmul_rn(x, x), __fmul_rn(y, y)), __fmul_rn(z, z));
    pts4[i] = make_float4(x, y, z, pn);
}

// ---------------------------------------------------------------------------
// Kernel 2: transpose fea (B,64,N) -> feaT (B,N,64)
// ---------------------------------------------------------------------------
__global__ __launch_bounds__(256) void k_tr(const float* __restrict__ fea,
                                            float* __restrict__ feaT) {
    __shared__ float tile[64][65];
    int b = blockIdx.y, n0 = blockIdx.x * 64;
    int t = threadIdx.x;
    int nl = t & 63, cb = t >> 6;
#pragma unroll
    for (int i = 0; i < 16; i++) {
        int c = cb * 16 + i;
        tile[nl][c] = fea[((long)b * 64 + c) * NN + n0 + nl];
    }
    __syncthreads();
    int cl = t & 63, nb = t >> 6;
#pragma unroll
    for (int i = 0; i < 16; i++) {
        int n = nb * 16 + i;
        feaT[((long)b * NN + n0 + n) * 64 + cl] = tile[n][cl];
    }
}

// ---------------------------------------------------------------------------
// Kernel 3: farthest point sampling. One block (512 thr) per batch.
// R12 verbatim (== v5, the measured optimum ~930 us). Five structural
// attacks (issue-count, barrier-count, 2x wave-count, Morton+skip) all
// regressed or were neutral: the ~2200 cyc/step floor is the two barrier
// round-trips + DPP chain, not VALU work. Packed v2f distance update,
// contract(off): bit-exact rn ops; value-only f32 DPP wave max; rare
// block-global winner path via equality scan + LDS atomicMin.
// ---------------------------------------------------------------------------
__global__ __launch_bounds__(512) void k_fps(const float4* __restrict__ pts4,
                                             float4* __restrict__ qpts,
                                             float* __restrict__ out) {
#pragma clang fp contract(off)
    __shared__ float xs[NN], ys[NN], zs[NN];
    __shared__ int scur[SS];
    __shared__ __align__(16) float redv[2][8];
    __shared__ int sidx[2];
    int b = blockIdx.x;
    int t = threadIdx.x;
    const float4* P = pts4 + (long)b * NN;

    // pair j, half h -> point p = t + (2j+h)*512
    v2f px[8], py[8], pz[8], dist[8];
#pragma unroll
    for (int j = 0; j < 8; j++) {
        int p0 = t + (2 * j) * 512;
        int p1 = t + (2 * j + 1) * 512;
        float4 a = P[p0];
        float4 c = P[p1];
        px[j] = v2f{a.x, c.x};
        py[j] = v2f{a.y, c.y};
        pz[j] = v2f{a.z, c.z};
        dist[j] = v2f{1e10f, 1e10f};
        xs[p0] = a.x; ys[p0] = a.y; zs[p0] = a.z;
        xs[p1] = c.x; ys[p1] = c.y; zs[p1] = c.z;
    }
    if (t == 0) { sidx[0] = 0x7FFFFFFF; sidx[1] = 0x7FFFFFFF; }
    __syncthreads();

    int cur = 0;
    for (int s = 0; s < SS; s++) {
        int par = s & 1;
        float cx = xs[cur], cy = ys[cur], cz = zs[cur];
        if (t == 0) scur[s] = cur;
        v2f cx2 = v2f{cx, cx}, cy2 = v2f{cy, cy}, cz2 = v2f{cz, cz};
#pragma unroll
        for (int j = 0; j < 8; j++) {
            v2f dx = px[j] - cx2;
            v2f dy = py[j] - cy2;
            v2f dz = pz[j] - cz2;
            v2f xx = dx * dx;
            v2f yy = dy * dy;
            v2f zz = dz * dz;
            v2f sm = xx + yy;
            v2f d = sm + zz;
            dist[j] = __builtin_elementwise_min(dist[j], d);
        }
        // value-only per-thread max: packed tree (7 pk-max) + final scalar
        v2f m01 = __builtin_elementwise_max(dist[0], dist[1]);
        v2f m23 = __builtin_elementwise_max(dist[2], dist[3]);
        v2f m45 = __builtin_elementwise_max(dist[4], dist[5]);
        v2f m67 = __builtin_elementwise_max(dist[6], dist[7]);
        v2f m03 = __builtin_elementwise_max(m01, m23);
        v2f m47 = __builtin_elementwise_max(m45, m67);
        v2f m07 = __builtin_elementwise_max(m03, m47);
        float bv = fmaxf(m07.x, m07.y);
        // 64-lane DPP f32 max; full-wave max lands in lane 63
        float wv = bv;
        wv = dpp_maxf<0x111, 0xF>(wv);   // row_shr:1
        wv = dpp_maxf<0x112, 0xF>(wv);   // row_shr:2
        wv = dpp_maxf<0x114, 0xF>(wv);   // row_shr:4
        wv = dpp_maxf<0x118, 0xF>(wv);   // row_shr:8
        wv = dpp_maxf<0x142, 0xA>(wv);   // row_bcast:15 (rows 1,3)
        wv = dpp_maxf<0x143, 0xC>(wv);   // row_bcast:31 (rows 2,3)
        if ((t & 63) == 63) redv[par][t >> 6] = wv;
        __syncthreads();                 // barrier 1
        float4 r0 = *(const float4*)redv[par];
        float4 r1 = *(const float4*)(redv[par] + 4);
        float gmax = fmaxf(fmax3(r0.x, r0.y, r0.z),
                           fmax3(r0.w, fmax3(r1.x, r1.y, r1.z), r1.w));
        // reset the OTHER sidx slot (used at s+1); barrier 2 separates it
        // from s+1's atomics.
        if (t == 0) sidx[1 - par] = 0x7FFFFFFF;
        if (bv == gmax) {
            // block-rare path (usually 1 thread): lowest matching ord
            int jj = 16;
#pragma unroll
            for (int j = 7; j >= 0; j--) {
                jj = (dist[j].y == gmax) ? (2 * j + 1) : jj;
                jj = (dist[j].x == gmax) ? (2 * j) : jj;
            }
            atomicMin(&sidx[par], t + jj * 512);
        }
        __syncthreads();                 // barrier 2
        cur = sidx[par];
    }
    __syncthreads();

    // epilogue: write new_coor (B,3,S) and query points from recorded indices
#pragma unroll
    for (int s = t; s < SS; s += 512) {
        int c = scur[s];
        float cx = xs[c], cy = ys[c], cz = zs[c];
        out[(long)b * 3 * SS + s]          = cx;
        out[(long)b * 3 * SS + SS + s]     = cy;
        out[(long)b * 3 * SS + 2 * SS + s] = cz;
        float qn = __fadd_rn(__fadd_rn(__fmul_rn(cx, cx), __fmul_rn(cy, cy)),
                             __fmul_rn(cz, cz));
        qpts[(long)b * SS + s] = make_float4(cx, cy, cz, qn);
    }
}

// ---------------------------------------------------------------------------
// Kernel 4 (FUSED knn+mlp): R12 structure (passed, absmax 0.0), with the MLP
// phase packed: output-channel pairs (a0,a1) accumulate via v_pk_fma_f32
// (__builtin_elementwise_fma on v2f, weights interleaved wab[c]={wa,wb}).
// Each half is the same IEEE fma in the same order as the scalar fmaf
// version -> bit-identical results, half the VALU issue (4352 -> 2176
// fma-slots per thread).
// ---------------------------------------------------------------------------
#define SKEW(p) ((p) + ((p) >> 5))
__global__ __launch_bounds__(64, 1) void k_knn_mlp(const float4* __restrict__ pts4,
                                                   const float* __restrict__ feaT,
                                                   const float4* __restrict__ qpts,
                                                   const float* __restrict__ W,
                                                   float* __restrict__ out) {
    __shared__ __align__(16) unsigned dk[NN + NN / 32];   // 33792 B
    __shared__ int sidxs[GG];
    float* grouped = (float*)dk;   // reused after pops: 32*68 floats (8704 B)

    int Q = blockIdx.x;                      // b*1024 + s
    int b = Q >> 10, s = Q & 1023;
    int l = threadIdx.x;
    float4 q = qpts[Q];
    const float4* P = pts4 + (long)b * NN;

    // ---- Phase 1: distance scan ----
    unsigned bmin = 0xFFFFFFFFu;
    int bpos = 0;
#pragma unroll 16
    for (int j = 0; j < 128; j++) {
        int p = j * 64 + l;
        float4 v = P[p];
        float dot = __fadd_rn(__fadd_rn(__fmul_rn(q.x, v.x), __fmul_rn(q.y, v.y)),
                              __fmul_rn(q.z, v.z));
        float d = __fadd_rn(__fsub_rn(q.w, __fmul_rn(2.0f, dot)), v.w);
        unsigned u = sortable(d);
        dk[SKEW(p)] = u;
        if (u < bmin) { bmin = u; bpos = p; }   // ascending p -> earliest index on tie
    }
    __syncthreads();

    // ---- Phase 2: W rows into registers, interleaved (latency overlaps pops) ----
    v2f wab[68];
    {
        const float* Wr = W + l * 67;
#pragma unroll
        for (int c = 0; c < 67; c++) {
            wab[c] = v2f{Wr[c], Wr[64 * 67 + c]};
        }
        wab[67] = v2f{0.f, 0.f};
    }

    // ---- Phase 3: 32 pops ----
    unsigned resv = 0;
    int resp = 0, pos0 = 0;
    for (int k = 0; k < GG; k++) {
        unsigned mv = bmin;
        mv = dpp_minu<0x111, 0xF>(mv);
        mv = dpp_minu<0x112, 0xF>(mv);
        mv = dpp_minu<0x114, 0xF>(mv);
        mv = dpp_minu<0x118, 0xF>(mv);
        mv = dpp_minu<0x142, 0xA>(mv);
        mv = dpp_minu<0x143, 0xC>(mv);
        unsigned wmin = (unsigned)__builtin_amdgcn_readlane((int)mv, 63);
        unsigned long long mask = __ballot(bmin == wmin);
        int wpos;
        if (__builtin_popcountll(mask) == 1) {
            int owner = __builtin_ctzll(mask);
            wpos = __builtin_amdgcn_readlane(bpos, owner);
        } else {
            unsigned long long kk =
                ((unsigned long long)bmin << 32) | (unsigned)bpos;
#pragma unroll
            for (int m = 1; m < 64; m <<= 1) {
                unsigned long long o = __shfl_xor(kk, m, 64);
                kk = (o < kk) ? o : kk;
            }
            wpos = (int)(kk & 0xFFFFFFFFull);
        }
        if (k == 0) pos0 = wpos;
        if (l == k) { resv = wmin; resp = wpos; }
        int own = wpos & 63;
        if (l == own) dk[SKEW(wpos)] = 0xFFFFFFFFu;   // invalidate popped slot
        __syncthreads();
        // cooperative rescan of owner's column (its 128 points)
        int p1 = l * 64 + own;
        int p2 = (l + 64) * 64 + own;
        unsigned v1 = dk[SKEW(p1)], v2 = dk[SKEW(p2)];
        bool c = v2 < v1;                 // p1 < p2, so tie keeps earliest
        unsigned cv = c ? v2 : v1;
        int cp = c ? p2 : p1;
        unsigned cm = cv;
        cm = dpp_minu<0x111, 0xF>(cm);
        cm = dpp_minu<0x112, 0xF>(cm);
        cm = dpp_minu<0x114, 0xF>(cm);
        cm = dpp_minu<0x118, 0xF>(cm);
        cm = dpp_minu<0x142, 0xA>(cm);
        cm = dpp_minu<0x143, 0xC>(cm);
        unsigned colmin = (unsigned)__builtin_amdgcn_readlane((int)cm, 63);
        unsigned long long m2 = __ballot(cv == colmin);
        int colpos;
        if (__builtin_popcountll(m2) == 1) {
            colpos = __builtin_amdgcn_readlane(cp, __builtin_ctzll(m2));
        } else {
            unsigned long long kk =
                ((unsigned long long)cv << 32) | (unsigned)cp;
#pragma unroll
            for (int m = 1; m < 64; m <<= 1) {
                unsigned long long o = __shfl_xor(kk, m, 64);
                kk = (o < kk) ? o : kk;
            }
            colpos = (int)(kk & 0xFFFFFFFFull);
        }
        if (l == own) { bmin = colmin; bpos = colpos; }
        __syncthreads();
    }

    // ---- Phase 4: final indices + gather into reused LDS ----
    if (l < GG) sidxs[l] = (resv > SORT_R2) ? pos0 : resp;   // radius filter
    __syncthreads();   // sidxs visible; dk dead from here on

    if (l < 32) {
        int idx = sidxs[l];
        float4 p = pts4[(long)b * NN + idx];
        float4 rc = make_float4(__fsub_rn(p.x, q.x), __fsub_rn(p.y, q.y),
                                __fsub_rn(p.z, q.z), 0.f);
        *(float4*)&grouped[l * 68 + 64] = rc;
    }
    {
        int g = l >> 1, half = l & 1;
        int idx = sidxs[g];
        const float4* f4 = (const float4*)(feaT + ((long)b * NN + idx) * 64);
#pragma unroll
        for (int k4 = 0; k4 < 8; k4++) {
            *(float4*)&grouped[g * 68 + half * 32 + k4 * 4] = f4[half * 8 + k4];
        }
    }
    __syncthreads();

    // ---- Phase 5: 1x1 conv + relu + max over group (packed pk_fma) ----
    v2f mm = v2f{-1e30f, -1e30f};
#pragma unroll 2
    for (int g = 0; g < GG; g++) {
        v2f a = v2f{0.f, 0.f};
#pragma unroll
        for (int c4 = 0; c4 < 17; c4++) {
            float4 gv = *(float4*)&grouped[g * 68 + c4 * 4];
            a = __builtin_elementwise_fma(v2f{gv.x, gv.x}, wab[4 * c4 + 0], a);
            a = __builtin_elementwise_fma(v2f{gv.y, gv.y}, wab[4 * c4 + 1], a);
            a = __builtin_elementwise_fma(v2f{gv.z, gv.z}, wab[4 * c4 + 2], a);
            a = __builtin_elementwise_fma(v2f{gv.w, gv.w}, wab[4 * c4 + 3], a);
        }
        mm = __builtin_elementwise_max(mm, a);
    }
    // outputs: (B,3,S) then (B,128,S); relu(max) == max(relu)
    out[49152 + ((long)b * 128 + l) * SS + s]      = fmaxf(mm.x, 0.f);
    out[49152 + ((long)b * 128 + l + 64) * SS + s] = fmaxf(mm.y, 0.f);
}

// ---------------------------------------------------------------------------
extern "C" void kernel_launch(void* const* d_in, const int* in_sizes, int n_in,
                              void* d_out, int out_size, void* d_ws, size_t ws_size,
                              hipStream_t stream) {
    const float* coor = (const float*)d_in[0];   // (16,3,8192)
    const float* fea  = (const float*)d_in[1];   // (16,64,8192)
    const float* Wm   = (const float*)d_in[2];   // (128,67)
    float* out = (float*)d_out;

    char* ws = (char*)d_ws;
    float4* pts4 = (float4*)ws;                               //  2 MB
    float*  feaT = (float*)(ws + 2097152);                    // 32 MB
    float4* qpts = (float4*)(ws + 2097152 + 33554432);        // 256 KB

    k_pts<<<(BB * NN) / 256, 256, 0, stream>>>(coor, pts4);
    k_tr<<<dim3(NN / 64, BB), 256, 0, stream>>>(fea, feaT);
    k_fps<<<BB, 512, 0, stream>>>(pts4, qpts, out);
    k_knn_mlp<<<BB * SS, 64, 0, stream>>>(pts4, feaT, qpts, Wm, out);
}